// Round 6
// baseline (28329.184 us; speedup 1.0000x reference)
//
#include <hip/hip_runtime.h>
#include <math.h>

#define SCALE_F 0.03125f   // 1/sqrt(1024)

// =====================================================================
// fp32 tiled GEMM: C[M,N] = A[M,K] @ (BT ? B[N,K]^T : B[K,N])
// EPI: 0 = none, 1 = silu
// =====================================================================
template<bool BT, int EPI>
__global__ __launch_bounds__(256) void gemm_nt(const float* __restrict__ A,
                                               const float* __restrict__ Bm,
                                               float* __restrict__ C,
                                               int M, int N, int K) {
  __shared__ float As[32][68];
  __shared__ float Bs[32][68];
  const int tid = threadIdx.x;
  const int n0 = blockIdx.x * 64;
  const int m0 = blockIdx.y * 64;
  const int i0 = (tid >> 4) * 4;
  const int j0 = (tid & 15) * 4;
  float acc[4][4] = {};

  for (int k0 = 0; k0 < K; k0 += 32) {
#pragma unroll
    for (int s = 0; s < 2; ++s) {
      int id = tid + 256 * s;
      int r = id >> 3, c4 = id & 7;
      float4 v = *(const float4*)&A[(size_t)(m0 + r) * K + k0 + c4 * 4];
      As[c4 * 4 + 0][r] = v.x; As[c4 * 4 + 1][r] = v.y;
      As[c4 * 4 + 2][r] = v.z; As[c4 * 4 + 3][r] = v.w;
    }
    if (BT) {
#pragma unroll
      for (int s = 0; s < 2; ++s) {
        int id = tid + 256 * s;
        int r = id >> 3, c4 = id & 7;
        float4 v = *(const float4*)&Bm[(size_t)(n0 + r) * K + k0 + c4 * 4];
        Bs[c4 * 4 + 0][r] = v.x; Bs[c4 * 4 + 1][r] = v.y;
        Bs[c4 * 4 + 2][r] = v.z; Bs[c4 * 4 + 3][r] = v.w;
      }
    } else {
#pragma unroll
      for (int s = 0; s < 2; ++s) {
        int id = tid + 256 * s;
        int kk = id >> 4, c4 = id & 15;
        float4 v = *(const float4*)&Bm[(size_t)(k0 + kk) * N + n0 + c4 * 4];
        *(float4*)&Bs[kk][c4 * 4] = v;
      }
    }
    __syncthreads();
#pragma unroll
    for (int kk = 0; kk < 32; ++kk) {
      float4 a = *(const float4*)&As[kk][i0];
      float4 b = *(const float4*)&Bs[kk][j0];
      float av[4] = {a.x, a.y, a.z, a.w};
      float bv[4] = {b.x, b.y, b.z, b.w};
#pragma unroll
      for (int ii = 0; ii < 4; ++ii)
#pragma unroll
        for (int jj = 0; jj < 4; ++jj)
          acc[ii][jj] = fmaf(av[ii], bv[jj], acc[ii][jj]);
    }
    __syncthreads();
  }

#pragma unroll
  for (int ii = 0; ii < 4; ++ii) {
    float4 v;
    float* vp = (float*)&v;
#pragma unroll
    for (int jj = 0; jj < 4; ++jj) {
      float x = acc[ii][jj];
      if (EPI == 1) x = x / (1.0f + __expf(-x));
      vp[jj] = x;
    }
    *(float4*)&C[(size_t)(m0 + i0 + ii) * N + n0 + j0] = v;
  }
}

// =====================================================================
// Coherent (agent-scope) helpers: all cross-wg data goes through these.
// =====================================================================
__device__ __forceinline__ float ald(const float* p) {
  return __hip_atomic_load(p, __ATOMIC_RELAXED, __HIP_MEMORY_SCOPE_AGENT);
}
__device__ __forceinline__ void ast(float* p, float v) {
  __hip_atomic_store(p, v, __ATOMIC_RELAXED, __HIP_MEMORY_SCOPE_AGENT);
}
__device__ __forceinline__ int ildi(const int* p) {
  return __hip_atomic_load(p, __ATOMIC_RELAXED, __HIP_MEMORY_SCOPE_AGENT);
}
__device__ __forceinline__ void iast(int* p, int v) {
  __hip_atomic_store(p, v, __ATOMIC_RELAXED, __HIP_MEMORY_SCOPE_AGENT);
}

// Rotated tape addressing: row- and column-direction both conflict-free-ish.
#define TIDX(n, e) ((n) * 64 + (((e) + (n)) & 63))

// Weight regs: 8 named float4 (32 floats/thread), 2 rows x 16 strided cols.
// Named SSA values only (HARD LESSON rounds 1-4: local arrays -> scratch
// under the immovable 128-VGPR budget -> 100 GB/launch scratch traffic).
#define WQL(R, Q) \
  float4 w##R##Q = make_float4(Wp[(R) * 1024 + 64 * (4 * (Q) + 0)], \
                               Wp[(R) * 1024 + 64 * (4 * (Q) + 1)], \
                               Wp[(R) * 1024 + 64 * (4 * (Q) + 2)], \
                               Wp[(R) * 1024 + 64 * (4 * (Q) + 3)]);

// One matvec micro-step: col cc = l + 64*(4Q+IDX); h_t delivers all 4
// batches in 2 b64 reads; 8 FMAs (2 rows x 4 batches).
#define MVC(Q, IDX, COMP) { \
  const int cc = l + 64 * (4 * (Q) + (IDX)); \
  float2 hA = *(const float2*)&h_t[6 * cc]; \
  float2 hB = *(const float2*)&h_t[6 * cc + 2]; \
  a00 = fmaf(w0##Q.COMP, hA.x, a00); a01 = fmaf(w0##Q.COMP, hA.y, a01); \
  a02 = fmaf(w0##Q.COMP, hB.x, a02); a03 = fmaf(w0##Q.COMP, hB.y, a03); \
  a10 = fmaf(w1##Q.COMP, hA.x, a10); a11 = fmaf(w1##Q.COMP, hA.y, a11); \
  a12 = fmaf(w1##Q.COMP, hB.x, a12); a13 = fmaf(w1##Q.COMP, hB.y, a13); }
#define MVQ(Q) MVC(Q, 0, x) MVC(Q, 1, y) MVC(Q, 2, z) MVC(Q, 3, w)

// =====================================================================
// Group-shared persistent scan: 256 wgs x 1024 threads (16 waves, 4/SIMD).
// 4 independent GROUPS of 64 wgs; group g serves batches 4g..4g+3.
// wg (g, b_loc = idx>>4, es = idx&15): owner of (batch bsel, e-slice es)
// AND producer of rows R0=[es*64+b_loc*16, +16) of BOTH W_h and W_write
// for ALL 4 group batches. Weights: 32 fp32/thread in named float4 regs.
// h is staged BATCH-TRANSPOSED in LDS: h_t[6d + b] -> one b64 read gives
// 2 batches; per-thread matvec LDS traffic = exactly the bytes needed
// (4x less than the row-major staging of the previous round).
// Per step, per group: 2 sync hops (single-writer flags, 64-lane poll):
//   A: owners publish h(j)+ps -> all stage h_t, matvec, publish Rh/wv+qp
//   B: owners gather own slices + q, softmax via rs=(1-wa)ws+wa*q,
//      tape lerp, read gather, h(j+1), ps, fA=j+1.
// =====================================================================
__global__ __launch_bounds__(1024) void scan_kernel(
    const float* __restrict__ W_h, const float* __restrict__ W_wr,
    const float* __restrict__ b_h, const float* __restrict__ gate,
    float* __restrict__ wx,       // [B][T][D]; rows overwritten with h*gate
    float* __restrict__ ps_g,     // [B][16][64] score partials (owner-pub)
    float* __restrict__ Rh_g,     // [B][1024]  (producer-published rows)
    float* __restrict__ wv_g,     // [B][1024]
    float* __restrict__ qp_g,     // [B][64]    q partials by in-group wg
    float* __restrict__ h_g,      // [B][D] (= d_out h_work_f slot)
    float* __restrict__ tape_out, // [B][64][D]
    int* __restrict__ flags) {    // fA[256], fB[256]
  const int tid  = threadIdx.x;
  const int wg   = blockIdx.x;
  const int g    = wg >> 6;        // group
  const int idx  = wg & 63;        // in-group index
  const int b_loc = idx >> 4;
  const int es   = idx & 15;
  const int gb   = g * 4;          // first batch of group
  const int bsel = gb + b_loc;     // owned batch
  const int E0   = es * 64;        // owned e-slice
  const int R0   = es * 64 + b_loc * 16;  // produced row base (both mats)
  const int w    = tid >> 6;       // wave 0..15
  const int lane = tid & 63;
  const int l    = lane;
  const int nw2  = tid >> 4;       // 0..63: tape slot n
  const int ks2  = tid & 15;       // 16-way e split (4 elems each)

  __shared__ float h_t[1024 * 6];    // 24 KB batch-transposed h (+2 pad)
  __shared__ float tape_l[64 * 64];  // rotated, 16 KB
  __shared__ float qtmp[8][4];
  __shared__ float ws_lds[64], wa_lds[64], attn_lds[64];
  __shared__ float wv_lds[64], Rh_lds[64], h_own[64], read_lds[64];
  __shared__ float q_lds;
  // Pad LDS past 80 KB so exactly 1 wg/CU (256 wgs <-> 256 CUs).
  __shared__ volatile float lds_pad[12288];
  lds_pad[tid] = 0.0f;

  int* fA = flags;
  int* fB = flags + 256;

  // ---- weight preload: wave w covers 2 rows: R0 + 2*(w&7) + {0,1} of
  // W_h (w<8) / W_wr (w>=8); lane l covers cols {l + 64i, i=0..15}. ----
  const float* Wp = ((w < 8) ? W_h : W_wr)
                    + (size_t)(R0 + ((w & 7) << 1)) * 1024 + l;
  WQL(0, 0) WQL(0, 1) WQL(0, 2) WQL(0, 3)
  WQL(1, 0) WQL(1, 1) WQL(1, 2) WQL(1, 3)

  for (int i = tid; i < 4096; i += 1024) tape_l[i] = 0.0f;

  float bh_r = 0.0f;
  if (w == 0) bh_r = b_h[E0 + lane];
  __syncthreads();

  // ---- prologue: h(1) = tanh(wx0 + b_h); ps (vs tape0=0) = 0 ----
  if (w == 0) {
    size_t xi = (size_t)bsel * 1048576 + E0 + lane;
    float hv = tanhf(wx[xi] + bh_r);
    h_own[lane] = hv;
    ast(&h_g[bsel * 1024 + E0 + lane], hv);
    wx[xi] = hv * gate[xi];                 // output row 0
  }
  if (tid < 64) ast(&ps_g[bsel * 1024 + es * 64 + tid], 0.0f);
  __syncthreads();
  if (tid == 0) {
    asm volatile("s_waitcnt vmcnt(0) lgkmcnt(0)" ::: "memory");
    iast(&fA[wg], 1);
  }

  for (int j = 1; j <= 1024; ++j) {
    const bool last = (j == 1024);

    // ---- hop A wait: all 64 in-group wgs published h(j) + ps ----
    if (w == 0) {
      const int* f = &fA[g * 64];
      for (;;) {
        int v = ildi(&f[lane]);
        if (__all(v >= j)) break;
        __builtin_amdgcn_s_sleep(2);
      }
    }
    __syncthreads();

    // ---- stage h(j) of 4 group batches, batch-transposed (4/thread) ----
#pragma unroll
    for (int r = 0; r < 4; ++r) {
      int i = tid + r * 1024;
      int bl = i >> 10, d = i & 1023;
      h_t[6 * d + bl] = ald(&h_g[(size_t)(gb + bl) * 1024 + d]);
    }
    // ps partial loads for own batch (consumed after matvec); tid<512
    float p0 = 0.0f, p1 = 0.0f;
    if (tid < 512) {
      int nwr = tid >> 3, ksb = tid & 7;
      p0 = ald(&ps_g[bsel * 1024 + (ksb * 2) * 64 + nwr]);
      p1 = ald(&ps_g[bsel * 1024 + (ksb * 2 + 1) * 64 + nwr]);
    }
    // wave0 prefetch of wx/gate row j (plain cached loads, own rows)
    float wxv = 0.0f, gv = 0.0f;
    size_t xj = 0;
    if (w == 0 && !last) {
      xj  = (size_t)bsel * 1048576 + (size_t)j * 1024 + E0 + lane;
      wxv = wx[xj];
      gv  = gate[xj];
    }
    __syncthreads();

    // ---- matvec: 2 rows x 4 batches, 16 cols/lane; 128 FMA/thread ----
    float a00 = 0.0f, a01 = 0.0f, a02 = 0.0f, a03 = 0.0f;
    float a10 = 0.0f, a11 = 0.0f, a12 = 0.0f, a13 = 0.0f;
    MVQ(0) MVQ(1) MVQ(2) MVQ(3)
    // ws reduce: ws[n] = sum over 16 owner partials (raw dot); tid<512
    if (tid < 512) {
      int nwr = tid >> 3, ksb = tid & 7;
      float s = p0 + p1;
      s += __shfl_xor(s, 1);
      s += __shfl_xor(s, 2);
      s += __shfl_xor(s, 4);
      if (ksb == 0) ws_lds[nwr] = s;
    }
    // full-wave butterfly: every lane ends with the row/batch sums
#pragma unroll
    for (int m = 1; m < 64; m <<= 1) {
      a00 += __shfl_xor(a00, m); a01 += __shfl_xor(a01, m);
      a02 += __shfl_xor(a02, m); a03 += __shfl_xor(a03, m);
      a10 += __shfl_xor(a10, m); a11 += __shfl_xor(a11, m);
      a12 += __shfl_xor(a12, m); a13 += __shfl_xor(a13, m);
    }
    if (l == 0) {
      const int gr0 = R0 + ((w & 7) << 1);
      float* dst = (w < 8) ? Rh_g : wv_g;
      ast(&dst[(size_t)(gb + 0) * 1024 + gr0], a00);
      ast(&dst[(size_t)(gb + 1) * 1024 + gr0], a01);
      ast(&dst[(size_t)(gb + 2) * 1024 + gr0], a02);
      ast(&dst[(size_t)(gb + 3) * 1024 + gr0], a03);
      ast(&dst[(size_t)(gb + 0) * 1024 + gr0 + 1], a10);
      ast(&dst[(size_t)(gb + 1) * 1024 + gr0 + 1], a11);
      ast(&dst[(size_t)(gb + 2) * 1024 + gr0 + 1], a12);
      ast(&dst[(size_t)(gb + 3) * 1024 + gr0 + 1], a13);
      if (w >= 8) {  // qp contribution: sum_r wv[r][b]*h[b][row r]
        qtmp[w - 8][0] = a00 * h_t[6 * gr0 + 0] + a10 * h_t[6 * (gr0 + 1) + 0];
        qtmp[w - 8][1] = a01 * h_t[6 * gr0 + 1] + a11 * h_t[6 * (gr0 + 1) + 1];
        qtmp[w - 8][2] = a02 * h_t[6 * gr0 + 2] + a12 * h_t[6 * (gr0 + 1) + 2];
        qtmp[w - 8][3] = a03 * h_t[6 * gr0 + 3] + a13 * h_t[6 * (gr0 + 1) + 3];
      }
    }
    __syncthreads();

    // ---- wave0: wa = softmax(SCALE*ws); wave1: qp publish ----
    if (w == 0) {
      float s = ws_lds[lane] * SCALE_F;
      float m = s;
#pragma unroll
      for (int off = 1; off < 64; off <<= 1) m = fmaxf(m, __shfl_xor(m, off));
      float ex = __expf(s - m);
      float sum = ex;
#pragma unroll
      for (int off = 1; off < 64; off <<= 1) sum += __shfl_xor(sum, off);
      wa_lds[lane] = ex / sum;
    } else if (w == 1) {
      if (lane < 32) {
        int bq = lane >> 3, ww = lane & 7;
        float s = qtmp[ww][bq];
        s += __shfl_xor(s, 1);
        s += __shfl_xor(s, 2);
        s += __shfl_xor(s, 4);
        if (ww == 0) ast(&qp_g[(size_t)(gb + bq) * 64 + idx], s);
      }
    }
    __syncthreads();
    if (tid == 0) {
      asm volatile("s_waitcnt vmcnt(0) lgkmcnt(0)" ::: "memory");
      iast(&fB[wg], j);
    }

    // ---- hop B wait: all 64 in-group producers published ----
    if (w == 0) {
      const int* f = &fB[g * 64];
      for (;;) {
        int v = ildi(&f[lane]);
        if (__all(v >= j)) break;
        __builtin_amdgcn_s_sleep(2);
      }
    }
    __syncthreads();

    // ---- gathers: own Rh/wv slices (contiguous) + q = sum of 64 qp ----
    if (w == 2) {
      wv_lds[lane] = ald(&wv_g[(size_t)bsel * 1024 + E0 + lane]);
    } else if (w == 3) {
      Rh_lds[lane] = ald(&Rh_g[(size_t)bsel * 1024 + E0 + lane]);
    } else if (w == 1) {
      float qv = ald(&qp_g[(size_t)bsel * 64 + lane]);
#pragma unroll
      for (int off = 1; off < 64; off <<= 1) qv += __shfl_xor(qv, off);
      if (lane == 0) q_lds = qv;
    }
    __syncthreads();

    // ---- wave0: attn = softmax(SCALE*rs), rs via identity ----
    if (w == 0 && !last) {
      float wsr = ws_lds[lane];
      float rs = fmaf(wa_lds[lane], q_lds - wsr, wsr) * SCALE_F;
      float m = rs;
#pragma unroll
      for (int off = 1; off < 64; off <<= 1) m = fmaxf(m, __shfl_xor(m, off));
      float ex = __expf(rs - m);
      float sum = ex;
#pragma unroll
      for (int off = 1; off < 64; off <<= 1) sum += __shfl_xor(sum, off);
      attn_lds[lane] = ex / sum;
    }
    // ---- tape lerp (all threads, 4 elems): tape += wa*(wv - tape) ----
    {
      float wa = wa_lds[nw2];
#pragma unroll
      for (int i = 0; i < 4; ++i) {
        int e = ks2 * 4 + i;
        int ix = TIDX(nw2, e);
        float t = tape_l[ix];
        tape_l[ix] = fmaf(wa, wv_lds[e] - t, t);
      }
    }
    if (last) break;
    __syncthreads();

    // ---- gather: read[e] = sum_n attn[n]*tape(j)[n][e] ----
    {
      int ge = tid >> 4, gn = tid & 15;
      float gsum = 0.0f;
#pragma unroll
      for (int i = 0; i < 4; ++i) {
        int n = gn * 4 + i;
        gsum = fmaf(attn_lds[n], tape_l[TIDX(n, ge)], gsum);
      }
      gsum += __shfl_xor(gsum, 1);
      gsum += __shfl_xor(gsum, 2);
      gsum += __shfl_xor(gsum, 4);
      gsum += __shfl_xor(gsum, 8);
      if (gn == 0) read_lds[ge] = gsum;
    }
    __syncthreads();

    // ---- h(j+1) = tanh(Rh + wx_j + read + b_h); publish + output ----
    if (w == 0) {
      float hv = tanhf(Rh_lds[lane] + wxv + read_lds[lane] + bh_r);
      h_own[lane] = hv;
      ast(&h_g[bsel * 1024 + E0 + lane], hv);
      wx[xj] = hv * gv;
    }
    __syncthreads();

    // ---- ps partials vs updated tape: ps[n] = sum_own_e h(j+1).tape ----
    {
      float s = 0.0f;
#pragma unroll
      for (int i = 0; i < 4; ++i) {
        int e = ks2 * 4 + i;
        s = fmaf(h_own[e], tape_l[TIDX(nw2, e)], s);
      }
      s += __shfl_xor(s, 1);
      s += __shfl_xor(s, 2);
      s += __shfl_xor(s, 4);
      s += __shfl_xor(s, 8);
      if (ks2 == 0) ast(&ps_g[bsel * 1024 + es * 64 + nw2], s);
    }
    __syncthreads();
    if (tid == 0) {
      asm volatile("s_waitcnt vmcnt(0) lgkmcnt(0)" ::: "memory");
      iast(&fA[wg], j + 1);
    }
  }

  // ---- epilogue: dump final tape slice (same elems this thread lerped) ----
#pragma unroll
  for (int i = 0; i < 4; ++i) {
    int e = ks2 * 4 + i;
    tape_out[(size_t)(bsel * 64 + nw2) * 1024 + E0 + e] = tape_l[TIDX(nw2, e)];
  }
}

// =====================================================================
extern "C" void kernel_launch(void* const* d_in, const int* in_sizes, int n_in,
                              void* d_out, int out_size, void* d_ws, size_t ws_size,
                              hipStream_t stream) {
  (void)in_sizes; (void)n_in; (void)out_size; (void)ws_size;
  const float* x      = (const float*)d_in[0];
  const float* in_w   = (const float*)d_in[1];
  const float* out_w  = (const float*)d_in[2];
  const float* gate_w = (const float*)d_in[3];
  const float* W_x    = (const float*)d_in[4];
  const float* W_h    = (const float*)d_in[5];
  const float* W_wr   = (const float*)d_in[6];
  const float* b_h    = (const float*)d_in[7];

  float* out  = (float*)d_out;                     // [16][1024][1024]
  float* tape = out + (size_t)16 * 1024 * 1024;    // [16][64][1024]
  float* hfin = tape + (size_t)16 * 64 * 1024;     // [16][1024]

  float* ws = (float*)d_ws;
  // scan-time small buffers overlay M1's region (M1 dead before scan)
  float* ps_g = ws;                    // [16][16][64] = 16384
  float* Rh_g = ws + 16384;            // [16][1024]   = 16384
  float* wv_g = ws + 32768;            // [16][1024]   = 16384
  float* qp_g = ws + 49152;            // [16][64]     = 1024
  int*   flg  = (int*)(ws + 50176);    // fA[256], fB[256]
  float* M1   = ws;                    // [1024][1024]
  float* wx   = ws + (1 << 20);        // [16][1024][1024]

  float* gate = out;                   // park gate in d_out region

  dim3 blk(256);
  gemm_nt<false, 0><<<dim3(16, 16), blk, 0, stream>>>(W_x, in_w, M1, 1024, 1024, 1024);
  gemm_nt<true, 1><<<dim3(16, 256), blk, 0, stream>>>(x, gate_w, gate, 16384, 1024, 1024);
  gemm_nt<true, 0><<<dim3(16, 256), blk, 0, stream>>>(x, M1, wx, 16384, 1024, 1024);
  hipMemsetAsync(flg, 0, 2048, stream);
  scan_kernel<<<256, 1024, 0, stream>>>(W_h, W_wr, b_h, gate, wx, ps_g, Rh_g,
                                        wv_g, qp_g, hfin, tape, flg);
  gemm_nt<true, 0><<<dim3(16, 256), blk, 0, stream>>>(wx, out_w, out, 16384, 1024, 1024);
}

// Round 7
// 10943.118 us; speedup vs baseline: 2.5888x; 2.5888x over previous
//
#include <hip/hip_runtime.h>
#include <math.h>

#define SCALE_F 0.03125f   // 1/sqrt(1024)

// =====================================================================
// fp32 tiled GEMM: C[M,N] = A[M,K] @ (BT ? B[N,K]^T : B[K,N])
// EPI: 0 = none, 1 = silu
// =====================================================================
template<bool BT, int EPI>
__global__ __launch_bounds__(256) void gemm_nt(const float* __restrict__ A,
                                               const float* __restrict__ Bm,
                                               float* __restrict__ C,
                                               int M, int N, int K) {
  __shared__ float As[32][68];
  __shared__ float Bs[32][68];
  const int tid = threadIdx.x;
  const int n0 = blockIdx.x * 64;
  const int m0 = blockIdx.y * 64;
  const int i0 = (tid >> 4) * 4;
  const int j0 = (tid & 15) * 4;
  float acc[4][4] = {};

  for (int k0 = 0; k0 < K; k0 += 32) {
#pragma unroll
    for (int s = 0; s < 2; ++s) {
      int id = tid + 256 * s;
      int r = id >> 3, c4 = id & 7;
      float4 v = *(const float4*)&A[(size_t)(m0 + r) * K + k0 + c4 * 4];
      As[c4 * 4 + 0][r] = v.x; As[c4 * 4 + 1][r] = v.y;
      As[c4 * 4 + 2][r] = v.z; As[c4 * 4 + 3][r] = v.w;
    }
    if (BT) {
#pragma unroll
      for (int s = 0; s < 2; ++s) {
        int id = tid + 256 * s;
        int r = id >> 3, c4 = id & 7;
        float4 v = *(const float4*)&Bm[(size_t)(n0 + r) * K + k0 + c4 * 4];
        Bs[c4 * 4 + 0][r] = v.x; Bs[c4 * 4 + 1][r] = v.y;
        Bs[c4 * 4 + 2][r] = v.z; Bs[c4 * 4 + 3][r] = v.w;
      }
    } else {
#pragma unroll
      for (int s = 0; s < 2; ++s) {
        int id = tid + 256 * s;
        int kk = id >> 4, c4 = id & 15;
        float4 v = *(const float4*)&Bm[(size_t)(k0 + kk) * N + n0 + c4 * 4];
        *(float4*)&Bs[kk][c4 * 4] = v;
      }
    }
    __syncthreads();
#pragma unroll
    for (int kk = 0; kk < 32; ++kk) {
      float4 a = *(const float4*)&As[kk][i0];
      float4 b = *(const float4*)&Bs[kk][j0];
      float av[4] = {a.x, a.y, a.z, a.w};
      float bv[4] = {b.x, b.y, b.z, b.w};
#pragma unroll
      for (int ii = 0; ii < 4; ++ii)
#pragma unroll
        for (int jj = 0; jj < 4; ++jj)
          acc[ii][jj] = fmaf(av[ii], bv[jj], acc[ii][jj]);
    }
    __syncthreads();
  }

#pragma unroll
  for (int ii = 0; ii < 4; ++ii) {
    float4 v;
    float* vp = (float*)&v;
#pragma unroll
    for (int jj = 0; jj < 4; ++jj) {
      float x = acc[ii][jj];
      if (EPI == 1) x = x / (1.0f + __expf(-x));
      vp[jj] = x;
    }
    *(float4*)&C[(size_t)(m0 + i0 + ii) * N + n0 + j0] = v;
  }
}

// =====================================================================
// Mailbox primitives: 8-byte (float value | 32-bit step tag), agent scope.
// Fuses flag+data into ONE LLC round trip (vs flag-publish -> flag-poll ->
// data-fetch). Single-word atomicity gives tearing-free (value, tag).
// =====================================================================
typedef unsigned long long u64;
__device__ __forceinline__ u64 ald64(const u64* p) {
  return __hip_atomic_load(p, __ATOMIC_RELAXED, __HIP_MEMORY_SCOPE_AGENT);
}
__device__ __forceinline__ void ast64(u64* p, u64 v) {
  __hip_atomic_store(p, v, __ATOMIC_RELAXED, __HIP_MEMORY_SCOPE_AGENT);
}
__device__ __forceinline__ u64 pk(float v, int j) {
  return ((u64)(unsigned)j << 32) | (u64)__float_as_uint(v);
}
__device__ __forceinline__ float pollv(const u64* p, int j) {
  u64 u = ald64(p);
  while ((unsigned)(u >> 32) != (unsigned)j) {
    __builtin_amdgcn_s_sleep(1);
    u = ald64(p);
  }
  return __uint_as_float((unsigned)u);
}

// Rotated tape addressing: row- and column-direction both conflict-free-ish.
#define TIDX(n, e) ((n) * 64 + (((e) + (n)) & 63))

// 64 named weight scalars/thread (one row of W_h AND W_wr, 32 strided cols).
// HARD LESSONS: (1) local arrays -> scratch (SROA runs pre-unroll);
// (2) VGPR budget = 65536/block_size, immovable (256thr->256, 512->128,
// 1024->64 measured); 64 floats + working set fits 128 (R5: VGPR=104).
#define REP32(M) M(0) M(1) M(2) M(3) M(4) M(5) M(6) M(7) M(8) M(9) M(10) \
  M(11) M(12) M(13) M(14) M(15) M(16) M(17) M(18) M(19) M(20) M(21) M(22) \
  M(23) M(24) M(25) M(26) M(27) M(28) M(29) M(30) M(31)

#define RW(i) const float wh##i = Whp[32 * (i)]; \
              const float ww##i = Wwp[32 * (i)];
#define MVI(i) { float4 hh = ht4[cseg + 32 * (i)]; \
  ah0 = fmaf(wh##i, hh.x, ah0); ah1 = fmaf(wh##i, hh.y, ah1); \
  ah2 = fmaf(wh##i, hh.z, ah2); ah3 = fmaf(wh##i, hh.w, ah3); \
  aw0 = fmaf(ww##i, hh.x, aw0); aw1 = fmaf(ww##i, hh.y, aw1); \
  aw2 = fmaf(ww##i, hh.z, aw2); aw3 = fmaf(ww##i, hh.w, aw3); }

// =====================================================================
// Group-shared persistent scan: 256 wgs x 512 threads (1 wg/CU, 8 waves).
// 4 groups of 64 wgs; group g serves batches 4g..4g+3. wg (b_loc, es):
// owner of (bsel, e-slice es) AND producer of rows R0=[es*64+b_loc*16,+16)
// of BOTH mats for all 4 batches. Thread (row=tid>>5, cseg=tid&31): row
// gr=R0+row of W_h AND W_wr, cols {cseg+32i}; h batch-transposed in LDS
// (h_t[4d+b]) -> one b128 read = 4 batches of a col -> 32 reads / 256 FMA.
// All cross-wg values are (value|tag) mailboxes: no flags, no flag hops.
// 6 barriers/step:
//  S0 stage h_t (polls) + ps polls + wx prefetch     |B1
//  S1 ws-reduce; matvec; publish Rh/wv pairs + qtmp  |B2
//  S2 w0:wa | w1:qp pub+poll+q+attn | w2:wv | w3:Rh  |B3
//  S3 tape lerp                                      |B4 (last: break)
//  S4 read gather                                    |B5
//  S5 w0: h tanh, publish h(j+1), wx out             |B6
//  S6 ps partials -> publish (tag j+1)               (loop)
// =====================================================================
__global__ __launch_bounds__(512) void scan_kernel(
    const float* __restrict__ W_h, const float* __restrict__ W_wr,
    const float* __restrict__ b_h, const float* __restrict__ gate,
    float* __restrict__ wx,       // [B][T][D]; rows overwritten with h*gate
    u64* __restrict__ h2,         // [B][1024] h mailboxes
    u64* __restrict__ ps2,        // [B][16][64] score-partial mailboxes
    u64* __restrict__ Rh2,        // [B][1024]
    u64* __restrict__ wv2,        // [B][1024]
    u64* __restrict__ qp2,        // [B][64]
    float* __restrict__ hfin,     // [B][1024] final h_work (plain)
    float* __restrict__ tape_out) // [B][64][1024]
{
  const int tid  = threadIdx.x;
  const int wg   = blockIdx.x;
  const int g    = wg >> 6;
  const int idx  = wg & 63;
  const int b_loc = idx >> 4;
  const int es   = idx & 15;
  const int gb   = g * 4;
  const int bsel = gb + b_loc;
  const int E0   = es * 64;
  const int R0   = es * 64 + b_loc * 16;
  const int w    = tid >> 6;
  const int lane = tid & 63;
  const int row  = tid >> 5;      // 0..15
  const int cseg = tid & 31;      // 32 col segments
  const int gr   = R0 + row;      // produced row (both mats)
  const int nwr  = tid >> 3;      // tape slot n
  const int ksb  = tid & 7;       // 8-elem e-block

  __shared__ float h_t[4096];       // batch-transposed h: h_t[4d+b], 16 KB
  __shared__ float tape_l[4096];    // rotated, 16 KB
  __shared__ float qtmp[16][4];
  __shared__ float ws_lds[64], wa_lds[64], attn_lds[64];
  __shared__ float wv_lds[64], Rh_lds[64], h_own[64], read_lds[64];
  // Pad past 80 KB: exactly 1 wg/CU (2 wgs/CU would halve a group member).
  __shared__ volatile float lds_pad[12288];
  lds_pad[tid] = 0.0f; lds_pad[tid + 512] = 0.0f;

  // ---- weight preload: row gr of W_h AND W_wr, cols cseg+32i ----
  const float* Whp = W_h + (size_t)gr * 1024 + cseg;
  const float* Wwp = W_wr + (size_t)gr * 1024 + cseg;
  REP32(RW)

  const float4* ht4 = (const float4*)h_t;

  for (int i = tid; i < 4096; i += 512) tape_l[i] = 0.0f;

  float bh_r = 0.0f;
  if (w == 0) bh_r = b_h[E0 + lane];
  __syncthreads();

  // ---- prologue: h(1) = tanh(wx0 + b_h) tag 1; ps tag 1 (= 0) ----
  if (w == 0) {
    size_t xi = (size_t)bsel * 1048576 + E0 + lane;
    float hv = tanhf(wx[xi] + bh_r);
    h_own[lane] = hv;
    ast64(&h2[(size_t)bsel * 1024 + E0 + lane], pk(hv, 1));
    wx[xi] = hv * gate[xi];                 // output row 0
  }
  if (tid < 64) ast64(&ps2[(size_t)bsel * 1024 + es * 64 + tid], pk(0.0f, 1));
  __syncthreads();

  for (int j = 1; j <= 1024; ++j) {
    const bool last = (j == 1024);

    // ---- S0: stage h(j) (mailbox polls), ps polls, wx prefetch ----
#pragma unroll
    for (int r = 0; r < 8; ++r) {
      int i = tid + r * 512;
      int bl = i >> 10, d = i & 1023;
      h_t[4 * d + bl] = pollv(&h2[(size_t)(gb + bl) * 1024 + d], j);
    }
    float p0 = pollv(&ps2[(size_t)bsel * 1024 + (ksb * 2) * 64 + nwr], j);
    float p1 = pollv(&ps2[(size_t)bsel * 1024 + (ksb * 2 + 1) * 64 + nwr], j);
    float wxv = 0.0f, gv = 0.0f;
    size_t xj = 0;
    if (w == 0 && !last) {
      xj  = (size_t)bsel * 1048576 + (size_t)j * 1024 + E0 + lane;
      wxv = wx[xj];
      gv  = gate[xj];
    }
    __syncthreads();   // B1

    // ---- S1: ws reduce; matvec; publish rows + qtmp ----
    {
      float s = p0 + p1;
      s += __shfl_xor(s, 1);
      s += __shfl_xor(s, 2);
      s += __shfl_xor(s, 4);
      if (ksb == 0) ws_lds[nwr] = s;
    }
    float ah0 = 0.0f, ah1 = 0.0f, ah2 = 0.0f, ah3 = 0.0f;
    float aw0 = 0.0f, aw1 = 0.0f, aw2 = 0.0f, aw3 = 0.0f;
    REP32(MVI)
#pragma unroll
    for (int m = 1; m < 32; m <<= 1) {
      ah0 += __shfl_xor(ah0, m); ah1 += __shfl_xor(ah1, m);
      ah2 += __shfl_xor(ah2, m); ah3 += __shfl_xor(ah3, m);
      aw0 += __shfl_xor(aw0, m); aw1 += __shfl_xor(aw1, m);
      aw2 += __shfl_xor(aw2, m); aw3 += __shfl_xor(aw3, m);
    }
    if (cseg == 0) {
      ast64(&Rh2[(size_t)(gb + 0) * 1024 + gr], pk(ah0, j));
      ast64(&Rh2[(size_t)(gb + 1) * 1024 + gr], pk(ah1, j));
      ast64(&Rh2[(size_t)(gb + 2) * 1024 + gr], pk(ah2, j));
      ast64(&Rh2[(size_t)(gb + 3) * 1024 + gr], pk(ah3, j));
      ast64(&wv2[(size_t)(gb + 0) * 1024 + gr], pk(aw0, j));
      ast64(&wv2[(size_t)(gb + 1) * 1024 + gr], pk(aw1, j));
      ast64(&wv2[(size_t)(gb + 2) * 1024 + gr], pk(aw2, j));
      ast64(&wv2[(size_t)(gb + 3) * 1024 + gr], pk(aw3, j));
      qtmp[row][0] = aw0 * h_t[4 * gr + 0];
      qtmp[row][1] = aw1 * h_t[4 * gr + 1];
      qtmp[row][2] = aw2 * h_t[4 * gr + 2];
      qtmp[row][3] = aw3 * h_t[4 * gr + 3];
    }
    __syncthreads();   // B2

    // ---- S2: wave-parallel: wa | qp+q+attn | wv gather | Rh gather ----
    if (w == 0) {
      float s = ws_lds[lane] * SCALE_F;
      float m = s;
#pragma unroll
      for (int off = 1; off < 64; off <<= 1) m = fmaxf(m, __shfl_xor(m, off));
      float ex = __expf(s - m);
      float sum = ex;
#pragma unroll
      for (int off = 1; off < 64; off <<= 1) sum += __shfl_xor(sum, off);
      wa_lds[lane] = ex / sum;
    } else if (w == 1) {
      // qp publish: reduce qtmp over 16 rows per batch
      int bq = lane >> 4, r = lane & 15;
      float s = qtmp[r][bq];
      s += __shfl_xor(s, 1); s += __shfl_xor(s, 2);
      s += __shfl_xor(s, 4); s += __shfl_xor(s, 8);
      if (r == 0) ast64(&qp2[(size_t)(gb + bq) * 64 + idx], pk(s, j));
      // poll all 64 qp of own batch -> q
      float qv = pollv(&qp2[(size_t)bsel * 64 + lane], j);
#pragma unroll
      for (int off = 1; off < 64; off <<= 1) qv += __shfl_xor(qv, off);
      // redundant own wa (avoids a cross-wave sync), rs identity, attn
      if (!last) {
        float wsr = ws_lds[lane];
        float sm = wsr * SCALE_F;
        float m = sm;
#pragma unroll
        for (int off = 1; off < 64; off <<= 1) m = fmaxf(m, __shfl_xor(m, off));
        float ex = __expf(sm - m);
        float sum = ex;
#pragma unroll
        for (int off = 1; off < 64; off <<= 1) sum += __shfl_xor(sum, off);
        float wa_l = ex / sum;
        float rs = fmaf(wa_l, qv - wsr, wsr) * SCALE_F;
        float m2 = rs;
#pragma unroll
        for (int off = 1; off < 64; off <<= 1) m2 = fmaxf(m2, __shfl_xor(m2, off));
        float ex2 = __expf(rs - m2);
        float sum2 = ex2;
#pragma unroll
        for (int off = 1; off < 64; off <<= 1) sum2 += __shfl_xor(sum2, off);
        attn_lds[lane] = ex2 / sum2;
      }
    } else if (w == 2) {
      wv_lds[lane] = pollv(&wv2[(size_t)bsel * 1024 + E0 + lane], j);
    } else if (w == 3) {
      Rh_lds[lane] = pollv(&Rh2[(size_t)bsel * 1024 + E0 + lane], j);
    }
    __syncthreads();   // B3

    // ---- S3: tape lerp ----
    {
      float wa = wa_lds[nwr];
#pragma unroll
      for (int i = 0; i < 8; ++i) {
        int e = ksb * 8 + i;
        int ix = TIDX(nwr, e);
        float t = tape_l[ix];
        tape_l[ix] = fmaf(wa, wv_lds[e] - t, t);
      }
    }
    if (last) break;
    __syncthreads();   // B4

    // ---- S4: read gather: read[e] = sum_n attn[n]*tape[n][e] ----
    {
      int ge = tid >> 3, gn = tid & 7;
      float gsum = 0.0f;
#pragma unroll
      for (int i = 0; i < 8; ++i) {
        int n = gn * 8 + i;
        gsum = fmaf(attn_lds[n], tape_l[TIDX(n, ge)], gsum);
      }
      gsum += __shfl_xor(gsum, 1);
      gsum += __shfl_xor(gsum, 2);
      gsum += __shfl_xor(gsum, 4);
      if (gn == 0) read_lds[ge] = gsum;
    }
    __syncthreads();   // B5

    // ---- S5: h(j+1) = tanh(Rh + wx_j + read + b_h); publish tag j+1 ----
    if (w == 0) {
      float hv = tanhf(Rh_lds[lane] + wxv + read_lds[lane] + bh_r);
      h_own[lane] = hv;
      ast64(&h2[(size_t)bsel * 1024 + E0 + lane], pk(hv, j + 1));
      wx[xj] = hv * gv;
    }
    __syncthreads();   // B6

    // ---- S6: ps partials vs updated tape -> publish tag j+1 ----
    {
      float s = 0.0f;
#pragma unroll
      for (int i = 0; i < 8; ++i) {
        int e = ksb * 8 + i;
        s = fmaf(h_own[e], tape_l[TIDX(nwr, e)], s);
      }
      s += __shfl_xor(s, 1);
      s += __shfl_xor(s, 2);
      s += __shfl_xor(s, 4);
      if (ksb == 0) ast64(&ps2[(size_t)bsel * 1024 + es * 64 + nwr], pk(s, j + 1));
    }
    // no barrier: next S0 touches h_t/mailboxes only; B1 orders h_t vs S1.
  }

  // ---- epilogue: final tape slice + final h_work ----
#pragma unroll
  for (int i = 0; i < 8; ++i) {
    int e = ksb * 8 + i;
    tape_out[(size_t)(bsel * 64 + nwr) * 1024 + E0 + e] = tape_l[TIDX(nwr, e)];
  }
  if (w == 0) hfin[(size_t)bsel * 1024 + E0 + lane] = h_own[lane];
}

// =====================================================================
extern "C" void kernel_launch(void* const* d_in, const int* in_sizes, int n_in,
                              void* d_out, int out_size, void* d_ws, size_t ws_size,
                              hipStream_t stream) {
  (void)in_sizes; (void)n_in; (void)out_size; (void)ws_size;
  const float* x      = (const float*)d_in[0];
  const float* in_w   = (const float*)d_in[1];
  const float* out_w  = (const float*)d_in[2];
  const float* gate_w = (const float*)d_in[3];
  const float* W_x    = (const float*)d_in[4];
  const float* W_h    = (const float*)d_in[5];
  const float* W_wr   = (const float*)d_in[6];
  const float* b_h    = (const float*)d_in[7];

  float* out  = (float*)d_out;                     // [16][1024][1024]
  float* tape = out + (size_t)16 * 1024 * 1024;    // [16][64][1024]
  float* hfin = tape + (size_t)16 * 64 * 1024;     // [16][1024]

  float* ws = (float*)d_ws;
  // scan-time mailboxes overlay M1's region (M1 dead before scan)
  u64* h2  = (u64*)ws;                  // 16K pairs -> 32768 floats
  u64* ps2 = (u64*)(ws + 32768);        // 16K pairs
  u64* Rh2 = (u64*)(ws + 65536);        // 16K pairs
  u64* wv2 = (u64*)(ws + 98304);        // 16K pairs
  u64* qp2 = (u64*)(ws + 131072);       // 1K pairs -> ends at 133120
  float* M1 = ws;                       // [1024][1024]
  float* wx = ws + (1 << 20);           // [16][1024][1024]

  float* gate = out;                    // park gate in d_out region

  dim3 blk(256);
  gemm_nt<false, 0><<<dim3(16, 16), blk, 0, stream>>>(W_x, in_w, M1, 1024, 1024, 1024);
  gemm_nt<true, 1><<<dim3(16, 256), blk, 0, stream>>>(x, gate_w, gate, 16384, 1024, 1024);
  gemm_nt<true, 0><<<dim3(16, 256), blk, 0, stream>>>(x, M1, wx, 16384, 1024, 1024);
  hipMemsetAsync(ws, 0, 133120 * sizeof(float), stream);   // zero tags
  scan_kernel<<<256, 512, 0, stream>>>(W_h, W_wr, b_h, gate, wx, h2, ps2,
                                       Rh2, wv2, qp2, hfin, tape);
  gemm_nt<true, 0><<<dim3(16, 256), blk, 0, stream>>>(wx, out_w, out, 16384, 1024, 1024);
}